// Round 2
// baseline (331.395 us; speedup 1.0000x reference)
//
#include <hip/hip_runtime.h>
#include <hip/hip_bf16.h>
#include <stdint.h>

// Problem constants (from reference)
// B=256 T=64 H=512 R*C=1024 -> D=1536, H1=H2=1024, A=64, M=B*T=16384
static constexpr int M_ROWS = 16384;
static constexpr int DIM_D  = 1536;
static constexpr int DIM_H1 = 1024;
static constexpr int DIM_H2 = 1024;

typedef short s8v  __attribute__((ext_vector_type(8)));   // 8 bf16 in 4 VGPRs
typedef float f4v  __attribute__((ext_vector_type(4)));

__device__ __forceinline__ unsigned short f2bf(float f) {
  unsigned int u = __float_as_uint(f);
  u += 0x7fffu + ((u >> 16) & 1u);   // round-to-nearest-even
  return (unsigned short)(u >> 16);
}
__device__ __forceinline__ float bf2f(unsigned short u) {
  return __uint_as_float(((unsigned int)u) << 16);
}

#define GLOAD16(g, l)                                                          \
  __builtin_amdgcn_global_load_lds(                                            \
      (const __attribute__((address_space(1))) unsigned int*)(g),              \
      (__attribute__((address_space(3))) unsigned int*)(l), 16, 0, 0)

// ---------------------------------------------------------------------------
// 1) Build X = concat(h, z) as bf16 [16384][1536]
// ---------------------------------------------------------------------------
__global__ __launch_bounds__(256) void prep_x(const float* __restrict__ h,
                                              const float* __restrict__ z,
                                              unsigned short* __restrict__ X) {
  int idx = blockIdx.x * 256 + threadIdx.x;     // 0 .. 16384*192-1 (8 elems each)
  int m = idx / 192;
  int c = (idx - m * 192) * 8;
  const float* s = (c < 512) ? (h + (size_t)m * 512 + c)
                             : (z + (size_t)m * 1024 + (c - 512));
  f4v f0 = *(const f4v*)s;
  f4v f1 = *(const f4v*)(s + 4);
  s8v o;
  o[0] = (short)f2bf(f0[0]); o[1] = (short)f2bf(f0[1]);
  o[2] = (short)f2bf(f0[2]); o[3] = (short)f2bf(f0[3]);
  o[4] = (short)f2bf(f1[0]); o[5] = (short)f2bf(f1[1]);
  o[6] = (short)f2bf(f1[2]); o[7] = (short)f2bf(f1[3]);
  *(s8v*)(X + (size_t)m * 1536 + c) = o;
}

// ---------------------------------------------------------------------------
// 2) Transpose W [K][N] fp32 -> WT [N][K] bf16
// ---------------------------------------------------------------------------
__global__ __launch_bounds__(256) void transpose_w(const float* __restrict__ W,
                                                   unsigned short* __restrict__ WT,
                                                   int K, int N) {
  __shared__ float tile[32][33];
  int tx = threadIdx.x & 31;
  int ty = threadIdx.x >> 5;  // 0..7
  int k0 = blockIdx.x * 32;
  int n0 = blockIdx.y * 32;
#pragma unroll
  for (int i = 0; i < 4; ++i)
    tile[ty + i * 8][tx] = W[(size_t)(k0 + ty + i * 8) * N + n0 + tx];
  __syncthreads();
#pragma unroll
  for (int i = 0; i < 4; ++i)
    WT[(size_t)(n0 + ty + i * 8) * K + k0 + tx] = f2bf(tile[tx][ty + i * 8]);
}

// ---------------------------------------------------------------------------
// 3) GEMM: C = silu(A @ W + bias) in bf16.  A [M][K] bf16, Bt = W^T [N][K] bf16.
//    128x128 tile, BK=64, 4 waves (2x2), each wave 64x64 via 4x4 16x16x32 MFMA.
//    LDS rows are 128 B with XOR-16B-slot swizzle; staging pre-swizzles the
//    global source so global_load_lds (linear dest) + swizzled ds_read match.
// ---------------------------------------------------------------------------
__global__ __launch_bounds__(256) void gemm_bias_silu(
    const unsigned short* __restrict__ A, const unsigned short* __restrict__ Bt,
    const float* __restrict__ bias, unsigned short* __restrict__ C,
    int M, int N, int K) {
  __shared__ char lds[2 * 128 * 128];
  char* const Als = lds;
  char* const Bls = lds + 128 * 128;

  const int tid = threadIdx.x;
  const int w = tid >> 6;
  const int l = tid & 63;
  const int wr = w >> 1, wc = w & 1;
  const int tm = blockIdx.y * 128;
  const int tn = blockIdx.x * 128;

  // staging lane constants: each inst covers 8 rows x 128 B (lane -> 16 B)
  const int srow = l >> 3;                 // row within 8-row group
  const int sk = ((l & 7) ^ srow) * 8;     // logical k-elem offset (pre-swizzled)

  const int l15 = l & 15;
  const int lh = l >> 4;

  f4v acc[4][4];
#pragma unroll
  for (int i = 0; i < 4; ++i)
#pragma unroll
    for (int j = 0; j < 4; ++j) acc[i][j] = (f4v){0.f, 0.f, 0.f, 0.f};

  for (int kt = 0; kt < K; kt += 64) {
#pragma unroll
    for (int i = 0; i < 4; ++i) {
      const int r0 = w * 32 + i * 8;
      GLOAD16(A  + (size_t)(tm + r0 + srow) * K + kt + sk, Als + r0 * 128);
      GLOAD16(Bt + (size_t)(tn + r0 + srow) * K + kt + sk, Bls + r0 * 128);
    }
    __syncthreads();   // drains vmcnt -> staged data visible
#pragma unroll
    for (int kk = 0; kk < 2; ++kk) {
      const int k16 = kk * 4 + lh;  // 16B slot index within 128B row
      s8v af[4], bf[4];
#pragma unroll
      for (int mi = 0; mi < 4; ++mi) {
        const int row = wr * 64 + mi * 16 + l15;
        af[mi] = *(const s8v*)(Als + row * 128 + ((k16 ^ (row & 7)) << 4));
      }
#pragma unroll
      for (int ni = 0; ni < 4; ++ni) {
        const int row = wc * 64 + ni * 16 + l15;
        bf[ni] = *(const s8v*)(Bls + row * 128 + ((k16 ^ (row & 7)) << 4));
      }
#pragma unroll
      for (int mi = 0; mi < 4; ++mi)
#pragma unroll
        for (int ni = 0; ni < 4; ++ni)
          acc[mi][ni] = __builtin_amdgcn_mfma_f32_16x16x32_bf16(
              af[mi], bf[ni], acc[mi][ni], 0, 0, 0);
    }
    __syncthreads();   // all waves done reading before next stage overwrites
  }

  // epilogue: bias + SiLU + bf16 store.  D layout: col=l&15, row=(l>>4)*4+r
#pragma unroll
  for (int ni = 0; ni < 4; ++ni) {
    const int col = tn + wc * 64 + ni * 16 + l15;
    const float bb = bias[col];
#pragma unroll
    for (int mi = 0; mi < 4; ++mi) {
#pragma unroll
      for (int r = 0; r < 4; ++r) {
        const int row = tm + wr * 64 + mi * 16 + lh * 4 + r;
        float v = acc[mi][ni][r] + bb;
        v = v / (1.f + __expf(-v));
        C[(size_t)row * N + col] = f2bf(v);
      }
    }
  }
}

// ---------------------------------------------------------------------------
// 4) value[m] = X2[m,:] . W3 + b3   (one wave per row, K=1024)
// ---------------------------------------------------------------------------
__global__ __launch_bounds__(256) void value_kernel(
    const unsigned short* __restrict__ X2, const float* __restrict__ W3,
    const float* __restrict__ b3, float* __restrict__ value) {
  const int m = blockIdx.x * 4 + (threadIdx.x >> 6);
  const int l = threadIdx.x & 63;
  const unsigned short* xr = X2 + (size_t)m * 1024 + l * 16;
  s8v v0 = *(const s8v*)xr;
  s8v v1 = *(const s8v*)(xr + 8);
  const f4v* wp = (const f4v*)(W3 + l * 16);
  f4v w0 = wp[0], w1 = wp[1], w2 = wp[2], w3v = wp[3];
  float s = 0.f;
#pragma unroll
  for (int j = 0; j < 4; ++j) s += bf2f((unsigned short)v0[j]) * w0[j];
#pragma unroll
  for (int j = 0; j < 4; ++j) s += bf2f((unsigned short)v0[4 + j]) * w1[j];
#pragma unroll
  for (int j = 0; j < 4; ++j) s += bf2f((unsigned short)v1[j]) * w2[j];
#pragma unroll
  for (int j = 0; j < 4; ++j) s += bf2f((unsigned short)v1[4 + j]) * w3v[j];
#pragma unroll
  for (int off = 32; off; off >>= 1) s += __shfl_down(s, off);
  if (l == 0) value[m] = s + b3[0];
}

// ---------------------------------------------------------------------------
// 5) TD(lambda) backward scan, adv = R_lam - value, accs[0] = sum(adv^2)
// ---------------------------------------------------------------------------
__global__ void td_kernel(const float* __restrict__ value,
                          const float* __restrict__ reward,
                          const float* __restrict__ cont,
                          float* __restrict__ adv, float* __restrict__ accs) {
  const int b = threadIdx.x;  // 256 threads, 1 block
  const float g = 0.99f, lam = 0.95f;
  float Rn = value[b * 64 + 63];
  adv[b * 64 + 63] = 0.f;
  float s = 0.f;
  for (int t = 62; t >= 0; --t) {
    const int i = b * 64 + t;
    float R = reward[i] + g * cont[i] * ((1.f - lam) * value[i + 1] + lam * Rn);
    float a = R - value[i];
    adv[i] = a;
    s += a * a;
    Rn = R;
  }
#pragma unroll
  for (int off = 32; off; off >>= 1) s += __shfl_down(s, off);
  __shared__ float red[4];
  if ((threadIdx.x & 63) == 0) red[threadIdx.x >> 6] = s;
  __syncthreads();
  if (threadIdx.x == 0) accs[0] = red[0] + red[1] + red[2] + red[3];
}

// ---------------------------------------------------------------------------
// 6) actor-loss partial sums: accs[1] += sum(lp*adv + nu*entropy)
// ---------------------------------------------------------------------------
__global__ __launch_bounds__(256) void actor_kernel(
    const float* __restrict__ action, const float* __restrict__ a_mu,
    const float* __restrict__ a_sigma, const float* __restrict__ adv,
    float* __restrict__ accs) {
  const float C1 = 0.91893853320467274f;  // 0.5*log(2*pi)
  const float NU = 0.001f;
  const size_t t = (size_t)blockIdx.x * 256 + threadIdx.x;
  const size_t base = t * 4;
  const int m = (int)(base >> 6);
  const float av = adv[m];
  f4v a = *(const f4v*)(action + base);
  f4v mu = *(const f4v*)(a_mu + base);
  f4v sg = *(const f4v*)(a_sigma + base);
  float s = 0.f;
#pragma unroll
  for (int j = 0; j < 4; ++j) {
    float d = (a[j] - mu[j]) / sg[j];
    float ls = __logf(sg[j]);
    float lp = -0.5f * d * d - ls - C1;
    s += lp * av + NU * (0.5f + C1 + ls);
  }
#pragma unroll
  for (int off = 32; off; off >>= 1) s += __shfl_down(s, off);
  __shared__ float red[4];
  if ((threadIdx.x & 63) == 0) red[threadIdx.x >> 6] = s;
  __syncthreads();
  if (threadIdx.x == 0) atomicAdd(&accs[1], red[0] + red[1] + red[2] + red[3]);
}

// ---------------------------------------------------------------------------
// 7) finalize
// ---------------------------------------------------------------------------
__global__ void fin_kernel(const float* __restrict__ accs, float* __restrict__ out) {
  out[0] = -accs[1] / 1048576.0f;        // B*T*A
  out[1] = 0.5f * accs[0] / 16384.0f;    // B*T
}

// ---------------------------------------------------------------------------
extern "C" void kernel_launch(void* const* d_in, const int* in_sizes, int n_in,
                              void* d_out, int out_size, void* d_ws, size_t ws_size,
                              hipStream_t stream) {
  const float* h       = (const float*)d_in[0];
  const float* z       = (const float*)d_in[1];
  const float* reward  = (const float*)d_in[2];
  const float* cont    = (const float*)d_in[3];
  const float* action  = (const float*)d_in[4];
  const float* a_mu    = (const float*)d_in[5];
  const float* a_sigma = (const float*)d_in[6];
  const float* W1      = (const float*)d_in[7];
  const float* b1      = (const float*)d_in[8];
  const float* W2      = (const float*)d_in[9];
  const float* b2      = (const float*)d_in[10];
  const float* W3      = (const float*)d_in[11];
  const float* b3      = (const float*)d_in[12];

  char* ws = (char*)d_ws;
  unsigned short* X   = (unsigned short*)(ws);              // 48 MB, reused as X2
  unsigned short* W1T = (unsigned short*)(ws + 50331648);   // 3 MB
  unsigned short* W2T = (unsigned short*)(ws + 53477376);   // 2 MB
  unsigned short* X1  = (unsigned short*)(ws + 55574528);   // 32 MB
  unsigned short* X2  = X;                                  // alias (X dead after GEMM1)
  float* value = (float*)(ws + 89128960);
  float* adv   = (float*)(ws + 89194496);
  float* accs  = (float*)(ws + 89260032);

  hipMemsetAsync(accs, 0, 16, stream);
  prep_x<<<12288, 256, 0, stream>>>(h, z, X);
  transpose_w<<<dim3(48, 32), 256, 0, stream>>>(W1, W1T, 1536, 1024);
  transpose_w<<<dim3(32, 32), 256, 0, stream>>>(W2, W2T, 1024, 1024);
  gemm_bias_silu<<<dim3(8, 128), 256, 0, stream>>>(X, W1T, b1, X1, 16384, 1024, 1536);
  gemm_bias_silu<<<dim3(8, 128), 256, 0, stream>>>(X1, W2T, b2, X2, 16384, 1024, 1024);
  value_kernel<<<4096, 256, 0, stream>>>(X2, W3, b3, value);
  td_kernel<<<1, 256, 0, stream>>>(value, reward, cont, adv, accs);
  actor_kernel<<<1024, 256, 0, stream>>>(action, a_mu, a_sigma, adv, accs);
  fin_kernel<<<1, 1, 0, stream>>>(accs, (float*)d_out);
}

// Round 3
// 289.974 us; speedup vs baseline: 1.1428x; 1.1428x over previous
//
#include <hip/hip_runtime.h>
#include <hip/hip_bf16.h>
#include <stdint.h>

typedef short s8v  __attribute__((ext_vector_type(8)));   // 8 bf16 in 4 VGPRs
typedef float f4v  __attribute__((ext_vector_type(4)));

__device__ __forceinline__ unsigned short f2bf(float f) {
  unsigned int u = __float_as_uint(f);
  u += 0x7fffu + ((u >> 16) & 1u);   // round-to-nearest-even
  return (unsigned short)(u >> 16);
}
__device__ __forceinline__ float bf2f(unsigned short u) {
  return __uint_as_float(((unsigned int)u) << 16);
}

#define GLOAD16(g, l)                                                          \
  __builtin_amdgcn_global_load_lds(                                            \
      (const __attribute__((address_space(1))) unsigned int*)(g),              \
      (__attribute__((address_space(3))) unsigned int*)(l), 16, 0, 0)

// ---------------------------------------------------------------------------
// 1) Build X = concat(h, z) as bf16 [16384][1536]
// ---------------------------------------------------------------------------
__global__ __launch_bounds__(256) void prep_x(const float* __restrict__ h,
                                              const float* __restrict__ z,
                                              unsigned short* __restrict__ X) {
  int idx = blockIdx.x * 256 + threadIdx.x;     // 16384*192 threads, 8 elems each
  int m = idx / 192;
  int c = (idx - m * 192) * 8;
  const float* s = (c < 512) ? (h + (size_t)m * 512 + c)
                             : (z + (size_t)m * 1024 + (c - 512));
  f4v f0 = *(const f4v*)s;
  f4v f1 = *(const f4v*)(s + 4);
  s8v o;
  o[0] = (short)f2bf(f0[0]); o[1] = (short)f2bf(f0[1]);
  o[2] = (short)f2bf(f0[2]); o[3] = (short)f2bf(f0[3]);
  o[4] = (short)f2bf(f1[0]); o[5] = (short)f2bf(f1[1]);
  o[6] = (short)f2bf(f1[2]); o[7] = (short)f2bf(f1[3]);
  *(s8v*)(X + (size_t)m * 1536 + c) = o;
}

// ---------------------------------------------------------------------------
// 2) Transpose W [K][N] fp32 -> WT [N][K] bf16
// ---------------------------------------------------------------------------
__global__ __launch_bounds__(256) void transpose_w(const float* __restrict__ W,
                                                   unsigned short* __restrict__ WT,
                                                   int K, int N) {
  __shared__ float tile[32][33];
  int tx = threadIdx.x & 31;
  int ty = threadIdx.x >> 5;  // 0..7
  int k0 = blockIdx.x * 32;
  int n0 = blockIdx.y * 32;
#pragma unroll
  for (int i = 0; i < 4; ++i)
    tile[ty + i * 8][tx] = W[(size_t)(k0 + ty + i * 8) * N + n0 + tx];
  __syncthreads();
#pragma unroll
  for (int i = 0; i < 4; ++i)
    WT[(size_t)(n0 + ty + i * 8) * K + k0 + tx] = f2bf(tile[tx][ty + i * 8]);
}

// ---------------------------------------------------------------------------
// 3) 256x256 GEMM, BK=64, 8 waves (2Mx4N), double-buffered LDS, counted-vmcnt
//    pipeline: issue next tile's 8 global_load_lds at iter start, 4 MFMA
//    phases (16 MFMA each, raw barriers, setprio), vmcnt(0) only at iter end.
//    LDS rows 128 B, XOR-16B-slot swizzle (same involution as verified R2).
//    FUSE: epilogue computes value += silu(acc+b2) . W3 instead of storing X2.
// ---------------------------------------------------------------------------
template<int K, bool FUSE>
__global__ __launch_bounds__(512) void gemm256(
    const unsigned short* __restrict__ A, const unsigned short* __restrict__ Bt,
    const float* __restrict__ bias, unsigned short* __restrict__ Cout,
    const float* __restrict__ W3, float* __restrict__ value) {
  constexpr int NOUT = 1024;
  constexpr int NT = K / 64;
  __shared__ char lds[131072];
  char* const A0 = lds;
  char* const B0 = lds + 32768;
  char* const A1 = lds + 65536;
  char* const B1 = lds + 98304;

  const int tid = threadIdx.x;
  const int w = tid >> 6, l = tid & 63;
  const int wr = w >> 2, wc = w & 3;           // 2 x 4 wave grid
  const int tm = blockIdx.x * 256;             // bx = M-tile (XCD locality)
  const int tn = blockIdx.y * 256;
  const int l15 = l & 15, lh = l >> 4;

  // staging: inst i covers rows [i*64, i*64+64); thread -> row tid>>3, slot tid&7
  const int sgrow = tid >> 3;
  const int sgk = ((tid & 7) ^ (sgrow & 7)) * 8;   // pre-swizzled k-elem offset
  const unsigned short* Ag = A  + (size_t)(tm + sgrow) * K + sgk;
  const unsigned short* Bg = Bt + (size_t)(tn + sgrow) * K + sgk;
  const int wb = w * 1024;                     // wave-uniform LDS sub-base

  f4v acc[8][4];
#pragma unroll
  for (int i = 0; i < 8; ++i)
#pragma unroll
    for (int j = 0; j < 4; ++j) acc[i][j] = (f4v){0.f, 0.f, 0.f, 0.f};

  // prologue: stage tile 0 -> buf0
#pragma unroll
  for (int i = 0; i < 4; ++i) {
    GLOAD16(Ag + (size_t)i * 64 * K, A0 + i * 8192 + wb);
    GLOAD16(Bg + (size_t)i * 64 * K, B0 + i * 8192 + wb);
  }
  asm volatile("s_waitcnt vmcnt(0)" ::: "memory");
  __builtin_amdgcn_s_barrier();

  auto iter = [&](int t, char* Ac, char* Bc, char* An, char* Bn) {
    // issue next tile's staging early: ~4 MFMA phases of latency cover
    if (t + 1 < NT) {
      const size_t ko = (size_t)(t + 1) * 64;
#pragma unroll
      for (int i = 0; i < 4; ++i) {
        GLOAD16(Ag + (size_t)i * 64 * K + ko, An + i * 8192 + wb);
        GLOAD16(Bg + (size_t)i * 64 * K + ko, Bn + i * 8192 + wb);
      }
    }
    s8v bf[4];
#pragma unroll
    for (int ph = 0; ph < 4; ++ph) {
      const int kk = ph >> 1, mh = ph & 1;
      const int k16 = kk * 4 + lh;             // logical 16B slot in 128B row
      if (mh == 0) {
#pragma unroll
        for (int ni = 0; ni < 4; ++ni) {
          const int row = wc * 64 + ni * 16 + l15;
          bf[ni] = *(const s8v*)(Bc + row * 128 + ((k16 ^ (row & 7)) << 4));
        }
      }
      s8v af[4];
#pragma unroll
      for (int mi = 0; mi < 4; ++mi) {
        const int row = wr * 128 + (mh * 4 + mi) * 16 + l15;
        af[mi] = *(const s8v*)(Ac + row * 128 + ((k16 ^ (row & 7)) << 4));
      }
      __builtin_amdgcn_s_setprio(1);
#pragma unroll
      for (int mi = 0; mi < 4; ++mi)
#pragma unroll
        for (int ni = 0; ni < 4; ++ni)
          acc[mh * 4 + mi][ni] = __builtin_amdgcn_mfma_f32_16x16x32_bf16(
              af[mi], bf[ni], acc[mh * 4 + mi][ni], 0, 0, 0);
      __builtin_amdgcn_s_setprio(0);
      __builtin_amdgcn_s_barrier();            // phase barrier (raw, no drain)
    }
    // next tile's loads must have landed in ALL waves before next iter reads
    asm volatile("s_waitcnt vmcnt(0)" ::: "memory");
    __builtin_amdgcn_s_barrier();
  };

  for (int t = 0; t < NT; t += 2) {            // NT even (24 / 16)
    iter(t,     A0, B0, A1, B1);
    iter(t + 1, A1, B1, A0, B0);
  }

  // epilogue.  D layout: col=l&15 within frag, row=(l>>4)*4+r  (verified R2)
  if constexpr (!FUSE) {
#pragma unroll
    for (int ni = 0; ni < 4; ++ni) {
      const int col = tn + wc * 64 + ni * 16 + l15;
      const float bb = bias[col];
#pragma unroll
      for (int mi = 0; mi < 8; ++mi) {
#pragma unroll
        for (int r = 0; r < 4; ++r) {
          const int row = tm + wr * 128 + mi * 16 + lh * 4 + r;
          float v = acc[mi][ni][r] + bb;
          v = v / (1.f + __expf(-v));
          Cout[(size_t)row * NOUT + col] = f2bf(v);
        }
      }
    }
  } else {
    float bb[4], w3[4];
#pragma unroll
    for (int ni = 0; ni < 4; ++ni) {
      const int col = tn + wc * 64 + ni * 16 + l15;
      bb[ni] = bias[col];
      w3[ni] = W3[col];
    }
#pragma unroll
    for (int mi = 0; mi < 8; ++mi) {
#pragma unroll
      for (int r = 0; r < 4; ++r) {
        float s = 0.f;
#pragma unroll
        for (int ni = 0; ni < 4; ++ni) {
          float v = acc[mi][ni][r] + bb[ni];
          v = v / (1.f + __expf(-v));
          s += v * w3[ni];
        }
        s += __shfl_xor(s, 1);
        s += __shfl_xor(s, 2);
        s += __shfl_xor(s, 4);
        s += __shfl_xor(s, 8);                 // sum over l15 group (16 lanes)
        if (l15 == 0)
          atomicAdd(&value[tm + wr * 128 + mi * 16 + lh * 4 + r], s);
      }
    }
  }
}

// ---------------------------------------------------------------------------
// 4) TD(lambda) backward scan (b3 folded in), adv, accs[0] = sum(adv^2)
// ---------------------------------------------------------------------------
__global__ void td_kernel(const float* __restrict__ value,
                          const float* __restrict__ reward,
                          const float* __restrict__ cont,
                          const float* __restrict__ b3,
                          float* __restrict__ adv, float* __restrict__ accs) {
  const int b = threadIdx.x;  // 256 threads, 1 block
  const float g = 0.99f, lam = 0.95f;
  const float vb = b3[0];
  float Rn = value[b * 64 + 63] + vb;
  adv[b * 64 + 63] = 0.f;
  float s = 0.f;
  for (int t = 62; t >= 0; --t) {
    const int i = b * 64 + t;
    float vn = value[i + 1] + vb;
    float R = reward[i] + g * cont[i] * ((1.f - lam) * vn + lam * Rn);
    float a = R - (value[i] + vb);
    adv[i] = a;
    s += a * a;
    Rn = R;
  }
#pragma unroll
  for (int off = 32; off; off >>= 1) s += __shfl_down(s, off);
  __shared__ float red[4];
  if ((threadIdx.x & 63) == 0) red[threadIdx.x >> 6] = s;
  __syncthreads();
  if (threadIdx.x == 0) accs[0] = red[0] + red[1] + red[2] + red[3];
}

// ---------------------------------------------------------------------------
// 5) actor-loss partial sums: accs[1] += sum(lp*adv + nu*entropy)
// ---------------------------------------------------------------------------
__global__ __launch_bounds__(256) void actor_kernel(
    const float* __restrict__ action, const float* __restrict__ a_mu,
    const float* __restrict__ a_sigma, const float* __restrict__ adv,
    float* __restrict__ accs) {
  const float C1 = 0.91893853320467274f;  // 0.5*log(2*pi)
  const float NU = 0.001f;
  const size_t t = (size_t)blockIdx.x * 256 + threadIdx.x;
  const size_t base = t * 4;
  const int m = (int)(base >> 6);
  const float av = adv[m];
  f4v a = *(const f4v*)(action + base);
  f4v mu = *(const f4v*)(a_mu + base);
  f4v sg = *(const f4v*)(a_sigma + base);
  float s = 0.f;
#pragma unroll
  for (int j = 0; j < 4; ++j) {
    float d = (a[j] - mu[j]) / sg[j];
    float ls = __logf(sg[j]);
    float lp = -0.5f * d * d - ls - C1;
    s += lp * av + NU * (0.5f + C1 + ls);
  }
#pragma unroll
  for (int off = 32; off; off >>= 1) s += __shfl_down(s, off);
  __shared__ float red[4];
  if ((threadIdx.x & 63) == 0) red[threadIdx.x >> 6] = s;
  __syncthreads();
  if (threadIdx.x == 0) atomicAdd(&accs[1], red[0] + red[1] + red[2] + red[3]);
}

// ---------------------------------------------------------------------------
// 6) finalize
// ---------------------------------------------------------------------------
__global__ void fin_kernel(const float* __restrict__ accs, float* __restrict__ out) {
  out[0] = -accs[1] / 1048576.0f;        // B*T*A
  out[1] = 0.5f * accs[0] / 16384.0f;    // B*T
}

// ---------------------------------------------------------------------------
extern "C" void kernel_launch(void* const* d_in, const int* in_sizes, int n_in,
                              void* d_out, int out_size, void* d_ws, size_t ws_size,
                              hipStream_t stream) {
  const float* h       = (const float*)d_in[0];
  const float* z       = (const float*)d_in[1];
  const float* reward  = (const float*)d_in[2];
  const float* cont    = (const float*)d_in[3];
  const float* action  = (const float*)d_in[4];
  const float* a_mu    = (const float*)d_in[5];
  const float* a_sigma = (const float*)d_in[6];
  const float* W1      = (const float*)d_in[7];
  const float* b1      = (const float*)d_in[8];
  const float* W2      = (const float*)d_in[9];
  const float* b2      = (const float*)d_in[10];
  const float* W3      = (const float*)d_in[11];
  const float* b3      = (const float*)d_in[12];

  char* ws = (char*)d_ws;
  unsigned short* X   = (unsigned short*)(ws);              // 48 MB
  unsigned short* W1T = (unsigned short*)(ws + 50331648);   // 3 MB
  unsigned short* W2T = (unsigned short*)(ws + 53477376);   // 2 MB
  unsigned short* X1  = (unsigned short*)(ws + 55574528);   // 32 MB
  float* value = (float*)(ws + 89128960);                   // 64 KB
  float* adv   = (float*)(ws + 89194496);                   // 64 KB
  float* accs  = (float*)(ws + 89260032);

  hipMemsetAsync(value, 0, 131088, stream);   // value + adv + accs
  prep_x<<<12288, 256, 0, stream>>>(h, z, X);
  transpose_w<<<dim3(48, 32), 256, 0, stream>>>(W1, W1T, 1536, 1024);
  transpose_w<<<dim3(32, 32), 256, 0, stream>>>(W2, W2T, 1024, 1024);
  gemm256<1536, false><<<dim3(64, 4), 512, 0, stream>>>(X, W1T, b1, X1, nullptr, nullptr);
  gemm256<1024, true><<<dim3(64, 4), 512, 0, stream>>>(X1, W2T, b2, nullptr, W3, value);
  td_kernel<<<1, 256, 0, stream>>>(value, reward, cont, b3, adv, accs);
  actor_kernel<<<1024, 256, 0, stream>>>(action, a_mu, a_sigma, adv, accs);
  fin_kernel<<<1, 1, 0, stream>>>(accs, (float*)d_out);
}

// Round 4
// 273.397 us; speedup vs baseline: 1.2121x; 1.0606x over previous
//
#include <hip/hip_runtime.h>
#include <hip/hip_bf16.h>
#include <stdint.h>

typedef short s8v  __attribute__((ext_vector_type(8)));   // 8 bf16 in 4 VGPRs
typedef float f4v  __attribute__((ext_vector_type(4)));

__device__ __forceinline__ unsigned short f2bf(float f) {
  unsigned int u = __float_as_uint(f);
  u += 0x7fffu + ((u >> 16) & 1u);   // round-to-nearest-even
  return (unsigned short)(u >> 16);
}

#define GLOAD16(g, l)                                                          \
  __builtin_amdgcn_global_load_lds(                                            \
      (const __attribute__((address_space(1))) unsigned int*)(g),              \
      (__attribute__((address_space(3))) unsigned int*)(l), 16, 0, 0)

// ---------------------------------------------------------------------------
// 1) Build X = concat(h, z) as bf16 [16384][1536]
// ---------------------------------------------------------------------------
__global__ __launch_bounds__(256) void prep_x(const float* __restrict__ h,
                                              const float* __restrict__ z,
                                              unsigned short* __restrict__ X) {
  int idx = blockIdx.x * 256 + threadIdx.x;     // 16384*192 threads, 8 elems each
  int m = idx / 192;
  int c = (idx - m * 192) * 8;
  const float* s = (c < 512) ? (h + (size_t)m * 512 + c)
                             : (z + (size_t)m * 1024 + (c - 512));
  f4v f0 = *(const f4v*)s;
  f4v f1 = *(const f4v*)(s + 4);
  s8v o;
  o[0] = (short)f2bf(f0[0]); o[1] = (short)f2bf(f0[1]);
  o[2] = (short)f2bf(f0[2]); o[3] = (short)f2bf(f0[3]);
  o[4] = (short)f2bf(f1[0]); o[5] = (short)f2bf(f1[1]);
  o[6] = (short)f2bf(f1[2]); o[7] = (short)f2bf(f1[3]);
  *(s8v*)(X + (size_t)m * 1536 + c) = o;
}

// ---------------------------------------------------------------------------
// 2) Transpose W [K][N] fp32 -> WT [N][K] bf16
// ---------------------------------------------------------------------------
__global__ __launch_bounds__(256) void transpose_w(const float* __restrict__ W,
                                                   unsigned short* __restrict__ WT,
                                                   int K, int N) {
  __shared__ float tile[32][33];
  int tx = threadIdx.x & 31;
  int ty = threadIdx.x >> 5;  // 0..7
  int k0 = blockIdx.x * 32;
  int n0 = blockIdx.y * 32;
#pragma unroll
  for (int i = 0; i < 4; ++i)
    tile[ty + i * 8][tx] = W[(size_t)(k0 + ty + i * 8) * N + n0 + tx];
  __syncthreads();
#pragma unroll
  for (int i = 0; i < 4; ++i)
    WT[(size_t)(n0 + ty + i * 8) * K + k0 + tx] = f2bf(tile[tx][ty + i * 8]);
}

// ---------------------------------------------------------------------------
// 3) 256x256 GEMM, BK=64, 8 waves (2Mx4N), double-buffered LDS.
//    m201-style phase: {ds_reads for this phase's MFMA + stage 1 half-tile of
//    tile t+1} BARRIER {lgkm waits; setprio; 16 MFMA; setprio} BARRIER.
//    vmcnt(0) once per K-tile, after phase 3's MFMA (last-staged HT has ~1
//    phase of cover; older HTs 2-4 phases).  LDS rows 128 B, XOR-16B-slot
//    swizzle (verified R2/R3, 0 bank conflicts).
//    FUSE: epilogue computes value += silu(acc+b2) . W3 instead of storing C.
// ---------------------------------------------------------------------------
template<int K, bool FUSE>
__global__ __launch_bounds__(512) void gemm256(
    const unsigned short* __restrict__ A, const unsigned short* __restrict__ Bt,
    const float* __restrict__ bias, unsigned short* __restrict__ Cout,
    const float* __restrict__ W3, float* __restrict__ value) {
  constexpr int NOUT = 1024;
  constexpr int NT = K / 64;
  __shared__ char lds[131072];

  const int tid = threadIdx.x;
  const int w = tid >> 6, l = tid & 63;
  const int wr = w >> 2, wc = w & 3;           // 2 x 4 wave grid
  const int tm = blockIdx.x * 256;             // bx = M-tile (XCD locality)
  const int tn = blockIdx.y * 256;
  const int l15 = l & 15, lh = l >> 4;

  // staging: thread -> row tid>>3 (0..63 within a 64-row inst group), slot tid&7
  const int srow = tid >> 3;
  const int sk = ((tid & 7) ^ (srow & 7)) * 8;     // pre-swizzled k-elem offset
  const unsigned short* Ag = A  + (size_t)(tm + srow) * K + sk;
  const unsigned short* Bg = Bt + (size_t)(tn + srow) * K + sk;
  const int wb = w * 1024;                     // wave-uniform LDS sub-base

  // half-tile p of a K-tile: p0=A rows0-127, p1=A rows128-255, p2=B0, p3=B1
  auto stage_ht = [&](int p, char* bufbase, int kt) {
    const unsigned short* g =
        (p < 2 ? Ag : Bg) + (size_t)(p & 1) * 128 * K + kt;
    char* d = bufbase + p * 16384 + wb;
    GLOAD16(g, d);
    GLOAD16(g + (size_t)64 * K, d + 8192);
  };

  f4v acc[8][4];
#pragma unroll
  for (int i = 0; i < 8; ++i)
#pragma unroll
    for (int j = 0; j < 4; ++j) acc[i][j] = (f4v){0.f, 0.f, 0.f, 0.f};

  // prologue: burst-stage tile 0 -> buf0
#pragma unroll
  for (int p = 0; p < 4; ++p) stage_ht(p, lds, 0);
  asm volatile("s_waitcnt vmcnt(0)" ::: "memory");
  __builtin_amdgcn_s_barrier();

  s8v bf[4];
  for (int t = 0; t < NT; ++t) {
    char* const cb = lds + ((t & 1) ? 65536 : 0);     // current buffer
    char* const nb = lds + ((t & 1) ? 0 : 65536);     // next buffer
    char* const Ab = cb;
    char* const Bb = cb + 32768;
    const bool st = (t + 1 < NT);
    const int nkt = (t + 1) * 64;
#pragma unroll
    for (int ph = 0; ph < 4; ++ph) {
      const int kk = ph >> 1, mh = ph & 1;
      const int k16 = kk * 4 + lh;             // logical 16B slot in 128B row
      if (mh == 0) {
#pragma unroll
        for (int ni = 0; ni < 4; ++ni) {
          const int row = wc * 64 + ni * 16 + l15;
          bf[ni] = *(const s8v*)(Bb + row * 128 + ((k16 ^ (row & 7)) << 4));
        }
      }
      s8v af[4];
#pragma unroll
      for (int mi = 0; mi < 4; ++mi) {
        const int row = wr * 128 + (mh * 4 + mi) * 16 + l15;
        af[mi] = *(const s8v*)(Ab + row * 128 + ((k16 ^ (row & 7)) << 4));
      }
      if (st) stage_ht(ph, nb, nkt);           // spread staging: 1 HT / phase
      __builtin_amdgcn_s_barrier();            // reads issued; MFMA interval
      __builtin_amdgcn_s_setprio(1);
#pragma unroll
      for (int mi = 0; mi < 4; ++mi)
#pragma unroll
        for (int ni = 0; ni < 4; ++ni)
          acc[mh * 4 + mi][ni] = __builtin_amdgcn_mfma_f32_16x16x32_bf16(
              af[mi], bf[ni], acc[mh * 4 + mi][ni], 0, 0, 0);
      __builtin_amdgcn_s_setprio(0);
      if (ph == 3)                             // once per K-tile: next tile landed
        asm volatile("s_waitcnt vmcnt(0)" ::: "memory");
      __builtin_amdgcn_s_barrier();
    }
  }

  // epilogue.  D layout: col=l&15 within frag, row=(l>>4)*4+r  (verified R2)
  if constexpr (!FUSE) {
#pragma unroll
    for (int ni = 0; ni < 4; ++ni) {
      const int col = tn + wc * 64 + ni * 16 + l15;
      const float bb = bias[col];
#pragma unroll
      for (int mi = 0; mi < 8; ++mi) {
#pragma unroll
        for (int r = 0; r < 4; ++r) {
          const int row = tm + wr * 128 + mi * 16 + lh * 4 + r;
          float v = acc[mi][ni][r] + bb;
          v = v / (1.f + __expf(-v));
          Cout[(size_t)row * NOUT + col] = f2bf(v);
        }
      }
    }
  } else {
    float bb[4], w3[4];
#pragma unroll
    for (int ni = 0; ni < 4; ++ni) {
      const int col = tn + wc * 64 + ni * 16 + l15;
      bb[ni] = bias[col];
      w3[ni] = W3[col];
    }
#pragma unroll
    for (int mi = 0; mi < 8; ++mi) {
#pragma unroll
      for (int r = 0; r < 4; ++r) {
        float s = 0.f;
#pragma unroll
        for (int ni = 0; ni < 4; ++ni) {
          float v = acc[mi][ni][r] + bb[ni];
          v = v / (1.f + __expf(-v));
          s += v * w3[ni];
        }
        s += __shfl_xor(s, 1);
        s += __shfl_xor(s, 2);
        s += __shfl_xor(s, 4);
        s += __shfl_xor(s, 8);                 // sum over 16-lane l15 group
        if (l15 == 0)
          atomicAdd(&value[tm + wr * 128 + mi * 16 + lh * 4 + r], s);
      }
    }
  }
}

// ---------------------------------------------------------------------------
// 4) Fused TD(lambda) scan + actor loss.  One block per batch row b.
//    accs[0] += sum_t adv^2, accs[1] += sum_{t,a} (lp*adv + nu*entropy)
// ---------------------------------------------------------------------------
__global__ __launch_bounds__(256) void td_actor(
    const float* __restrict__ value, const float* __restrict__ reward,
    const float* __restrict__ cont, const float* __restrict__ b3,
    const float* __restrict__ action, const float* __restrict__ a_mu,
    const float* __restrict__ a_sigma, float* __restrict__ accs) {
  __shared__ float vv[64], rr[64], cc[64], adv_s[64];
  const int b = blockIdx.x, tid = threadIdx.x;
  if (tid < 64) {
    vv[tid] = value[b * 64 + tid] + b3[0];
    rr[tid] = reward[b * 64 + tid];
    cc[tid] = cont[b * 64 + tid];
  }
  __syncthreads();
  if (tid == 0) {
    const float g = 0.99f, lam = 0.95f;
    float Rn = vv[63];
    adv_s[63] = 0.f;
    float s2 = 0.f;
    for (int t = 62; t >= 0; --t) {
      float R = rr[t] + g * cc[t] * ((1.f - lam) * vv[t + 1] + lam * Rn);
      float a = R - vv[t];
      adv_s[t] = a;
      s2 += a * a;
      Rn = R;
    }
    atomicAdd(&accs[0], s2);
  }
  __syncthreads();
  // actor terms: 64 t x 64 a = 4096 elems, 16 per thread; t = tid>>2 constant
  const float C1 = 0.91893853320467274f;  // 0.5*log(2*pi)
  const float NU = 0.001f;
  const float av = adv_s[tid >> 2];
  const size_t base = (size_t)b * 4096 + tid * 16;
  float s = 0.f;
#pragma unroll
  for (int j = 0; j < 4; ++j) {
    f4v a  = *(const f4v*)(action  + base + j * 4);
    f4v mu = *(const f4v*)(a_mu    + base + j * 4);
    f4v sg = *(const f4v*)(a_sigma + base + j * 4);
#pragma unroll
    for (int i = 0; i < 4; ++i) {
      float d = (a[i] - mu[i]) / sg[i];
      float ls = __logf(sg[i]);
      float lp = -0.5f * d * d - ls - C1;
      s += lp * av + NU * (0.5f + C1 + ls);
    }
  }
#pragma unroll
  for (int off = 32; off; off >>= 1) s += __shfl_down(s, off);
  __shared__ float red[4];
  if ((tid & 63) == 0) red[tid >> 6] = s;
  __syncthreads();
  if (tid == 0) atomicAdd(&accs[1], red[0] + red[1] + red[2] + red[3]);
}

// ---------------------------------------------------------------------------
// 5) finalize
// ---------------------------------------------------------------------------
__global__ void fin_kernel(const float* __restrict__ accs, float* __restrict__ out) {
  out[0] = -accs[1] / 1048576.0f;        // B*T*A
  out[1] = 0.5f * accs[0] / 16384.0f;    // B*T
}

// ---------------------------------------------------------------------------
extern "C" void kernel_launch(void* const* d_in, const int* in_sizes, int n_in,
                              void* d_out, int out_size, void* d_ws, size_t ws_size,
                              hipStream_t stream) {
  const float* h       = (const float*)d_in[0];
  const float* z       = (const float*)d_in[1];
  const float* reward  = (const float*)d_in[2];
  const float* cont    = (const float*)d_in[3];
  const float* action  = (const float*)d_in[4];
  const float* a_mu    = (const float*)d_in[5];
  const float* a_sigma = (const float*)d_in[6];
  const float* W1      = (const float*)d_in[7];
  const float* b1      = (const float*)d_in[8];
  const float* W2      = (const float*)d_in[9];
  const float* b2      = (const float*)d_in[10];
  const float* W3      = (const float*)d_in[11];
  const float* b3      = (const float*)d_in[12];

  char* ws = (char*)d_ws;
  unsigned short* X   = (unsigned short*)(ws);              // 48 MB
  unsigned short* W1T = (unsigned short*)(ws + 50331648);   // 3 MB
  unsigned short* W2T = (unsigned short*)(ws + 53477376);   // 2 MB
  unsigned short* X1  = (unsigned short*)(ws + 55574528);   // 32 MB
  float* value = (float*)(ws + 89128960);                   // 64 KB
  float* accs  = (float*)(ws + 89194496);                   // 16 B

  hipMemsetAsync(value, 0, 65552, stream);    // value + accs
  prep_x<<<12288, 256, 0, stream>>>(h, z, X);
  transpose_w<<<dim3(48, 32), 256, 0, stream>>>(W1, W1T, 1536, 1024);
  transpose_w<<<dim3(32, 32), 256, 0, stream>>>(W2, W2T, 1024, 1024);
  gemm256<1536, false><<<dim3(64, 4), 512, 0, stream>>>(X, W1T, b1, X1, nullptr, nullptr);
  gemm256<1024, true><<<dim3(64, 4), 512, 0, stream>>>(X1, W2T, b2, nullptr, W3, value);
  td_actor<<<256, 256, 0, stream>>>(value, reward, cont, b3, action, a_mu, a_sigma, accs);
  fin_kernel<<<1, 1, 0, stream>>>(accs, (float*)d_out);
}

// Round 5
// 265.309 us; speedup vs baseline: 1.2491x; 1.0305x over previous
//
#include <hip/hip_runtime.h>
#include <hip/hip_bf16.h>
#include <stdint.h>

typedef short s8v  __attribute__((ext_vector_type(8)));   // 8 bf16 in 4 VGPRs
typedef float f4v  __attribute__((ext_vector_type(4)));

__device__ __forceinline__ unsigned short f2bf(float f) {
  unsigned int u = __float_as_uint(f);
  u += 0x7fffu + ((u >> 16) & 1u);   // round-to-nearest-even
  return (unsigned short)(u >> 16);
}

#define GLOAD16(g, l)                                                          \
  __builtin_amdgcn_global_load_lds(                                            \
      (const __attribute__((address_space(1))) unsigned int*)(g),              \
      (__attribute__((address_space(3))) unsigned int*)(l), 16, 0, 0)

// ---------------------------------------------------------------------------
// 1) Build X = concat(h, z) as bf16 [16384][1536]
// ---------------------------------------------------------------------------
__global__ __launch_bounds__(256) void prep_x(const float* __restrict__ h,
                                              const float* __restrict__ z,
                                              unsigned short* __restrict__ X) {
  int idx = blockIdx.x * 256 + threadIdx.x;     // 16384*192 threads, 8 elems each
  int m = idx / 192;
  int c = (idx - m * 192) * 8;
  const float* s = (c < 512) ? (h + (size_t)m * 512 + c)
                             : (z + (size_t)m * 1024 + (c - 512));
  f4v f0 = *(const f4v*)s;
  f4v f1 = *(const f4v*)(s + 4);
  s8v o;
  o[0] = (short)f2bf(f0[0]); o[1] = (short)f2bf(f0[1]);
  o[2] = (short)f2bf(f0[2]); o[3] = (short)f2bf(f0[3]);
  o[4] = (short)f2bf(f1[0]); o[5] = (short)f2bf(f1[1]);
  o[6] = (short)f2bf(f1[2]); o[7] = (short)f2bf(f1[3]);
  *(s8v*)(X + (size_t)m * 1536 + c) = o;
}

// ---------------------------------------------------------------------------
// 2) Transpose W [K][N] fp32 -> WT [N][K] bf16
// ---------------------------------------------------------------------------
__global__ __launch_bounds__(256) void transpose_w(const float* __restrict__ W,
                                                   unsigned short* __restrict__ WT,
                                                   int K, int N) {
  __shared__ float tile[32][33];
  int tx = threadIdx.x & 31;
  int ty = threadIdx.x >> 5;  // 0..7
  int k0 = blockIdx.x * 32;
  int n0 = blockIdx.y * 32;
#pragma unroll
  for (int i = 0; i < 4; ++i)
    tile[ty + i * 8][tx] = W[(size_t)(k0 + ty + i * 8) * N + n0 + tx];
  __syncthreads();
#pragma unroll
  for (int i = 0; i < 4; ++i)
    WT[(size_t)(n0 + ty + i * 8) * K + k0 + tx] = f2bf(tile[tx][ty + i * 8]);
}

// ---------------------------------------------------------------------------
// 3) 256x256 GEMM, BK=32 K-steps, 8 waves (2Mx4N), 4-deep LDS ring (4x32KB).
//    Counted-vmcnt pipeline: stage tile t+3 while computing tile t; at entry
//    of tile t wait vmcnt(8) (tiles t+1,t+2 stay in flight) + ONE barrier.
//    Sub-tile rows are 64B; swizzle unit = 2 rows (128B):
//      u_phys = ((row&1)*4 | k16) ^ ((row>>1)&7)   (involution, bank-uniform)
//    Staging pre-swizzles the per-lane GLOBAL source; LDS dest stays linear.
//    FUSE: epilogue computes value += silu(acc+b2) . W3 instead of storing C.
// ---------------------------------------------------------------------------
template<int K, bool FUSE>
__global__ __launch_bounds__(512) void gemm256(
    const unsigned short* __restrict__ A, const unsigned short* __restrict__ Bt,
    const float* __restrict__ bias, unsigned short* __restrict__ Cout,
    const float* __restrict__ W3, float* __restrict__ value) {
  constexpr int NOUT = 1024;
  constexpr int NT = K / 32;
  __shared__ char lds[131072];

  const int tid = threadIdx.x;
  const int w = tid >> 6, l = tid & 63;
  const int wr = w >> 2, wc = w & 3;           // 2 x 4 wave grid
  const int tm = blockIdx.x * 256;             // bx = M-tile (XCD locality)
  const int tn = blockIdx.y * 256;
  const int l15 = l & 15, lh = l >> 4;

  // staging thread constants: physical slot (rp=tid>>3, u=tid&7) holds
  // logical row = rp*2 + (ul>>2), k-slot = ul&3, with ul = u ^ (rp&7).
  const int ul   = (tid & 7) ^ ((tid >> 3) & 7);
  const int srow = ((tid >> 3) << 1) + (ul >> 2);   // 0..127 within a sweep
  const int sk   = (ul & 3) * 8;                    // k elem offset
  const unsigned short* Ag = A  + (size_t)(tm + srow) * K + sk;
  const unsigned short* Bg = Bt + (size_t)(tn + srow) * K + sk;
  const int wb = w * 1024;

  // ds_read swizzled base offsets; frag mi/ni adds mi*1024 (row +16 -> rp +8,
  // (rp&7) unchanged -> pure +1024 byte offset).
  const int ra = wr * 128 + l15;
  const int rb = wc * 64 + l15;
  const int aoff = (ra >> 1) * 128 + (((((ra & 1) << 2) | lh) ^ ((ra >> 1) & 7)) << 4);
  const int boff = 16384 + (rb >> 1) * 128 + (((((rb & 1) << 2) | lh) ^ ((rb >> 1) & 7)) << 4);

  f4v acc[8][4];
#pragma unroll
  for (int i = 0; i < 8; ++i)
#pragma unroll
    for (int j = 0; j < 4; ++j) acc[i][j] = (f4v){0.f, 0.f, 0.f, 0.f};

  // stage tile t (A 16KB in 2 sweeps + B 16KB in 2 sweeps) into slot t&3
  auto stage = [&](int t) {
    char* d = lds + (t & 3) * 32768 + wb;
    const int kt = t * 32;
    GLOAD16(Ag + kt, d);
    GLOAD16(Ag + (size_t)128 * K + kt, d + 8192);
    GLOAD16(Bg + kt, d + 16384);
    GLOAD16(Bg + (size_t)128 * K + kt, d + 24576);
  };

  stage(0); stage(1); stage(2);   // 12 loads in flight

#define MFMA4(mi, av)                                                          \
  acc[mi][0] = __builtin_amdgcn_mfma_f32_16x16x32_bf16(av, bf0, acc[mi][0], 0, 0, 0); \
  acc[mi][1] = __builtin_amdgcn_mfma_f32_16x16x32_bf16(av, bf1, acc[mi][1], 0, 0, 0); \
  acc[mi][2] = __builtin_amdgcn_mfma_f32_16x16x32_bf16(av, bf2, acc[mi][2], 0, 0, 0); \
  acc[mi][3] = __builtin_amdgcn_mfma_f32_16x16x32_bf16(av, bf3, acc[mi][3], 0, 0, 0);

#define TILE(t, VM)                                                            \
  {                                                                            \
    asm volatile(VM ::: "memory");                                             \
    __builtin_amdgcn_s_barrier();                                              \
    char* const sb = lds + ((t) & 3) * 32768;                                  \
    s8v bf0 = *(const s8v*)(sb + boff);                                        \
    s8v bf1 = *(const s8v*)(sb + boff + 1024);                                 \
    s8v bf2 = *(const s8v*)(sb + boff + 2048);                                 \
    s8v bf3 = *(const s8v*)(sb + boff + 3072);                                 \
    s8v a0 = *(const s8v*)(sb + aoff);                                         \
    s8v a1 = *(const s8v*)(sb + aoff + 1024);                                  \
    s8v a2 = *(const s8v*)(sb + aoff + 2048);                                  \
    s8v a3 = *(const s8v*)(sb + aoff + 3072);                                  \
    if ((t) + 3 < NT) stage((t) + 3);                                          \
    __builtin_amdgcn_s_setprio(1);                                             \
    MFMA4(0, a0) MFMA4(1, a1) MFMA4(2, a2) MFMA4(3, a3)                        \
    __builtin_amdgcn_s_setprio(0);                                             \
    a0 = *(const s8v*)(sb + aoff + 4096);                                      \
    a1 = *(const s8v*)(sb + aoff + 5120);                                      \
    a2 = *(const s8v*)(sb + aoff + 6144);                                      \
    a3 = *(const s8v*)(sb + aoff + 7168);                                      \
    __builtin_amdgcn_s_setprio(1);                                             \
    MFMA4(4, a0) MFMA4(5, a1) MFMA4(6, a2) MFMA4(7, a3)                        \
    __builtin_amdgcn_s_setprio(0);                                             \
  }

  for (int t = 0; t < NT - 2; ++t) TILE(t, "s_waitcnt vmcnt(8)")
  TILE(NT - 2, "s_waitcnt vmcnt(4)")
  TILE(NT - 1, "s_waitcnt vmcnt(0)")

#undef TILE
#undef MFMA4

  // epilogue.  D layout: col=l&15 within frag, row=(l>>4)*4+r  (verified R2)
  if constexpr (!FUSE) {
#pragma unroll
    for (int ni = 0; ni < 4; ++ni) {
      const int col = tn + wc * 64 + ni * 16 + l15;
      const float bb = bias[col];
#pragma unroll
      for (int mi = 0; mi < 8; ++mi) {
#pragma unroll
        for (int r = 0; r < 4; ++r) {
          const int row = tm + wr * 128 + mi * 16 + lh * 4 + r;
          float v = acc[mi][ni][r] + bb;
          v = v / (1.f + __expf(-v));
          Cout[(size_t)row * NOUT + col] = f2bf(v);
        }
      }
    }
  } else {
    float bb[4], w3[4];
#pragma unroll
    for (int ni = 0; ni < 4; ++ni) {
      const int col = tn + wc * 64 + ni * 16 + l15;
      bb[ni] = bias[col];
      w3[ni] = W3[col];
    }
#pragma unroll
    for (int mi = 0; mi < 8; ++mi) {
#pragma unroll
      for (int r = 0; r < 4; ++r) {
        float s = 0.f;
#pragma unroll
        for (int ni = 0; ni < 4; ++ni) {
          float v = acc[mi][ni][r] + bb[ni];
          v = v / (1.f + __expf(-v));
          s += v * w3[ni];
        }
        s += __shfl_xor(s, 1);
        s += __shfl_xor(s, 2);
        s += __shfl_xor(s, 4);
        s += __shfl_xor(s, 8);                 // sum over 16-lane l15 group
        if (l15 == 0)
          atomicAdd(&value[tm + wr * 128 + mi * 16 + lh * 4 + r], s);
      }
    }
  }
}

// ---------------------------------------------------------------------------
// 4) Fused TD(lambda) scan + actor loss.  One block per batch row b.
// ---------------------------------------------------------------------------
__global__ __launch_bounds__(256) void td_actor(
    const float* __restrict__ value, const float* __restrict__ reward,
    const float* __restrict__ cont, const float* __restrict__ b3,
    const float* __restrict__ action, const float* __restrict__ a_mu,
    const float* __restrict__ a_sigma, float* __restrict__ accs) {
  __shared__ float vv[64], rr[64], cc[64], adv_s[64];
  const int b = blockIdx.x, tid = threadIdx.x;
  if (tid < 64) {
    vv[tid] = value[b * 64 + tid] + b3[0];
    rr[tid] = reward[b * 64 + tid];
    cc[tid] = cont[b * 64 + tid];
  }
  __syncthreads();
  if (tid == 0) {
    const float g = 0.99f, lam = 0.95f;
    float Rn = vv[63];
    adv_s[63] = 0.f;
    float s2 = 0.f;
    for (int t = 62; t >= 0; --t) {
      float R = rr[t] + g * cc[t] * ((1.f - lam) * vv[t + 1] + lam * Rn);
      float a = R - vv[t];
      adv_s[t] = a;
      s2 += a * a;
      Rn = R;
    }
    atomicAdd(&accs[0], s2);
  }
  __syncthreads();
  const float C1 = 0.91893853320467274f;  // 0.5*log(2*pi)
  const float NU = 0.001f;
  const float av = adv_s[tid >> 2];
  const size_t base = (size_t)b * 4096 + tid * 16;
  float s = 0.f;
#pragma unroll
  for (int j = 0; j < 4; ++j) {
    f4v a  = *(const f4v*)(action  + base + j * 4);
    f4v mu = *(const f4v*)(a_mu    + base + j * 4);
    f4v sg = *(const f4v*)(a_sigma + base + j * 4);
#pragma unroll
    for (int i = 0; i < 4; ++i) {
      float d = (a[i] - mu[i]) / sg[i];
      float ls = __logf(sg[i]);
      float lp = -0.5f * d * d - ls - C1;
      s += lp * av + NU * (0.5f + C1 + ls);
    }
  }
#pragma unroll
  for (int off = 32; off; off >>= 1) s += __shfl_down(s, off);
  __shared__ float red[4];
  if ((tid & 63) == 0) red[tid >> 6] = s;
  __syncthreads();
  if (tid == 0) atomicAdd(&accs[1], red[0] + red[1] + red[2] + red[3]);
}

// ---------------------------------------------------------------------------
// 5) finalize
// ---------------------------------------------------------------------------
__global__ void fin_kernel(const float* __restrict__ accs, float* __restrict__ out) {
  out[0] = -accs[1] / 1048576.0f;        // B*T*A
  out[1] = 0.5f * accs[0] / 16384.0f;    // B*T
}

// ---------------------------------------------------------------------------
extern "C" void kernel_launch(void* const* d_in, const int* in_sizes, int n_in,
                              void* d_out, int out_size, void* d_ws, size_t ws_size,
                              hipStream_t stream) {
  const float* h       = (const float*)d_in[0];
  const float* z       = (const float*)d_in[1];
  const float* reward  = (const float*)d_in[2];
  const float* cont    = (const float*)d_in[3];
  const float* action  = (const float*)d_in[4];
  const float* a_mu    = (const float*)d_in[5];
  const float* a_sigma = (const float*)d_in[6];
  const float* W1      = (const float*)d_in[7];
  const float* b1      = (const float*)d_in[8];
  const float* W2      = (const float*)d_in[9];
  const float* b2      = (const float*)d_in[10];
  const float* W3      = (const float*)d_in[11];
  const float* b3      = (const float*)d_in[12];

  char* ws = (char*)d_ws;
  unsigned short* X   = (unsigned short*)(ws);              // 48 MB
  unsigned short* W1T = (unsigned short*)(ws + 50331648);   // 3 MB
  unsigned short* W2T = (unsigned short*)(ws + 53477376);   // 2 MB
  unsigned short* X1  = (unsigned short*)(ws + 55574528);   // 32 MB
  float* value = (float*)(ws + 89128960);                   // 64 KB
  float* accs  = (float*)(ws + 89194496);                   // 16 B

  hipMemsetAsync(value, 0, 65552, stream);    // value + accs
  prep_x<<<12288, 256, 0, stream>>>(h, z, X);
  transpose_w<<<dim3(48, 32), 256, 0, stream>>>(W1, W1T, 1536, 1024);
  transpose_w<<<dim3(32, 32), 256, 0, stream>>>(W2, W2T, 1024, 1024);
  gemm256<1536, false><<<dim3(64, 4), 512, 0, stream>>>(X, W1T, b1, X1, nullptr, nullptr);
  gemm256<1024, true><<<dim3(64, 4), 512, 0, stream>>>(X1, W2T, b2, nullptr, W3, value);
  td_actor<<<256, 256, 0, stream>>>(value, reward, cont, b3, action, a_mu, a_sigma, accs);
  fin_kernel<<<1, 1, 0, stream>>>(accs, (float*)d_out);
}

// Round 6
// 261.104 us; speedup vs baseline: 1.2692x; 1.0161x over previous
//
#include <hip/hip_runtime.h>
#include <hip/hip_bf16.h>
#include <stdint.h>

typedef short s8v  __attribute__((ext_vector_type(8)));   // 8 bf16 in 4 VGPRs
typedef float f4v  __attribute__((ext_vector_type(4)));

__device__ __forceinline__ unsigned short f2bf(float f) {
  unsigned int u = __float_as_uint(f);
  u += 0x7fffu + ((u >> 16) & 1u);   // round-to-nearest-even
  return (unsigned short)(u >> 16);
}

#define GLOAD16(g, l)                                                          \
  __builtin_amdgcn_global_load_lds(                                            \
      (const __attribute__((address_space(1))) unsigned int*)(g),              \
      (__attribute__((address_space(3))) unsigned int*)(l), 16, 0, 0)

// ---------------------------------------------------------------------------
// 1) Merged prep: X = concat(h,z) bf16 [16384][1536]; W1T, W2T transposes.
//    blocks [0,12288): prep_x; [12288,13824): W1T; [13824,14848): W2T
// ---------------------------------------------------------------------------
__global__ __launch_bounds__(256) void prep_all(
    const float* __restrict__ h, const float* __restrict__ z,
    unsigned short* __restrict__ X,
    const float* __restrict__ W1, unsigned short* __restrict__ W1T,
    const float* __restrict__ W2, unsigned short* __restrict__ W2T) {
  __shared__ float tile[32][33];
  const int bid = blockIdx.x, tid = threadIdx.x;
  if (bid < 12288) {
    int idx = bid * 256 + tid;        // 16384*192 threads, 8 elems each
    int m = idx / 192;
    int c = (idx - m * 192) * 8;
    const float* s = (c < 512) ? (h + (size_t)m * 512 + c)
                               : (z + (size_t)m * 1024 + (c - 512));
    f4v f0 = *(const f4v*)s;
    f4v f1 = *(const f4v*)(s + 4);
    s8v o;
    o[0] = (short)f2bf(f0[0]); o[1] = (short)f2bf(f0[1]);
    o[2] = (short)f2bf(f0[2]); o[3] = (short)f2bf(f0[3]);
    o[4] = (short)f2bf(f1[0]); o[5] = (short)f2bf(f1[1]);
    o[6] = (short)f2bf(f1[2]); o[7] = (short)f2bf(f1[3]);
    *(s8v*)(X + (size_t)m * 1536 + c) = o;
    return;
  }
  const float* W;
  unsigned short* WT;
  int K, loc;
  if (bid < 13824) { W = W1; WT = W1T; K = 1536; loc = bid - 12288;
                     // 48 k-tiles x 32 n-tiles
  } else           { W = W2; WT = W2T; K = 1024; loc = bid - 13824; }
  const int kt = (K == 1536) ? (loc % 48) : (loc % 32);
  const int nt = (K == 1536) ? (loc / 48) : (loc / 32);
  const int k0 = kt * 32, n0 = nt * 32;
  const int tx = tid & 31, ty = tid >> 5;   // ty 0..7
#pragma unroll
  for (int i = 0; i < 4; ++i)
    tile[ty + i * 8][tx] = W[(size_t)(k0 + ty + i * 8) * 1024 + n0 + tx];
  __syncthreads();
#pragma unroll
  for (int i = 0; i < 4; ++i)
    WT[(size_t)(n0 + ty + i * 8) * K + k0 + tx] = f2bf(tile[tx][ty + i * 8]);
}

// ---------------------------------------------------------------------------
// 2) 128x256 GEMM, BK=32, 8 waves (2Mx4N -> wave 64x64), 3-slot LDS ring
//    (3 x 24KB = 72KB -> 2 blocks/CU, 4 waves/SIMD).  Counted vmcnt(3):
//    stage tile t+2 during tile t (3 gload_lds/wave/tile).  One raw barrier
//    per K-tile.  Swizzle: 2-row/128B unit, u_phys = ((r&1)<<2|k16)^(rp&7),
//    staging pre-swizzles the global source (verified R2-R5, 0 conflicts).
//    FUSE: per-block LDS-reduced partial dot with W3 -> value_part[ny][row].
// ---------------------------------------------------------------------------
template<int K, bool FUSE>
__global__ __launch_bounds__(512, 4) void gemm128(
    const unsigned short* __restrict__ A, const unsigned short* __restrict__ Bt,
    const float* __restrict__ bias, unsigned short* __restrict__ Cout,
    const float* __restrict__ W3, float* __restrict__ value_part) {
  constexpr int NT = K / 32;
  __shared__ char lds[73728];                  // 3 slots x (A 8KB + B 16KB)

  const int tid = threadIdx.x;
  const int w = tid >> 6, l = tid & 63;
  const int wr = w >> 2, wc = w & 3;           // 2M x 4N wave grid
  const int tm = blockIdx.x * 128;             // bx = M-tile (XCD locality)
  const int tn = blockIdx.y * 256;
  const int l15 = l & 15, lh = l >> 4;

  // staging: physical slot (rp=tid>>3, u=tid&7); ul=u^(rp&7);
  // logical row = rp*2 + (ul>>2), k elem = (ul&3)*8
  const int ul   = (tid & 7) ^ ((tid >> 3) & 7);
  const int srow = ((tid >> 3) << 1) + (ul >> 2);   // 0..127 per sweep
  const int sk   = (ul & 3) * 8;
  const unsigned short* Ag = A  + (size_t)(tm + srow) * K + sk;
  const unsigned short* Bg = Bt + (size_t)(tn + srow) * K + sk;
  const int wb = w * 1024;                     // wave sub-base within a sweep

  // swizzled ds_read base offsets (k16 = lh, 0..3); frag step = +1024 B
  const int ra = wr * 64 + l15;
  const int rb = wc * 64 + l15;
  const int aoff = (ra >> 1) * 128 + (((((ra & 1) << 2) | lh) ^ ((ra >> 1) & 7)) << 4);
  const int boff = 8192 + (rb >> 1) * 128 + (((((rb & 1) << 2) | lh) ^ ((rb >> 1) & 7)) << 4);

  f4v acc[4][4];
#pragma unroll
  for (int i = 0; i < 4; ++i)
#pragma unroll
    for (int j = 0; j < 4; ++j) acc[i][j] = (f4v){0.f, 0.f, 0.f, 0.f};

  // stage tile t into slot offset so: A 1 sweep, B 2 sweeps (3 vmcnt items)
  auto stage = [&](int t, int so) {
    char* d = lds + so + wb;
    const int kt = t * 32;
    GLOAD16(Ag + kt, d);
    GLOAD16(Bg + kt, d + 8192);
    GLOAD16(Bg + (size_t)128 * K + kt, d + 16384);
  };

  stage(0, 0); stage(1, 24576);                // 6 loads in flight

#define MFMA4(mi, av)                                                          \
  acc[mi][0] = __builtin_amdgcn_mfma_f32_16x16x32_bf16(av, bf0, acc[mi][0], 0, 0, 0); \
  acc[mi][1] = __builtin_amdgcn_mfma_f32_16x16x32_bf16(av, bf1, acc[mi][1], 0, 0, 0); \
  acc[mi][2] = __builtin_amdgcn_mfma_f32_16x16x32_bf16(av, bf2, acc[mi][2], 0, 0, 0); \
  acc[mi][3] = __builtin_amdgcn_mfma_f32_16x16x32_bf16(av, bf3, acc[mi][3], 0, 0, 0);

#define TILE(t, coff, soff, ST, VM)                                            \
  {                                                                            \
    asm volatile(VM ::: "memory");                                             \
    __builtin_amdgcn_s_barrier();                                              \
    char* const sb = lds + (coff);                                             \
    s8v bf0 = *(const s8v*)(sb + boff);                                        \
    s8v bf1 = *(const s8v*)(sb + boff + 1024);                                 \
    s8v bf2 = *(const s8v*)(sb + boff + 2048);                                 \
    s8v bf3 = *(const s8v*)(sb + boff + 3072);                                 \
    s8v a0 = *(const s8v*)(sb + aoff);                                         \
    s8v a1 = *(const s8v*)(sb + aoff + 1024);                                  \
    if (ST) stage((t) + 2, (soff));                                            \
    __builtin_amdgcn_s_setprio(1);                                             \
    MFMA4(0, a0) MFMA4(1, a1)                                                  \
    __builtin_amdgcn_s_setprio(0);                                             \
    a0 = *(const s8v*)(sb + aoff + 2048);                                      \
    a1 = *(const s8v*)(sb + aoff + 3072);                                      \
    __builtin_amdgcn_s_setprio(1);                                             \
    MFMA4(2, a0) MFMA4(3, a1)                                                  \
    __builtin_amdgcn_s_setprio(0);                                             \
  }

  int coff = 0, soff = 49152;                  // soff = slot of tile t+2
  for (int t = 0; t < NT - 1; ++t) {
    TILE(t, coff, soff, (t + 2 < NT), "s_waitcnt vmcnt(3)")
    coff = (coff == 49152) ? 0 : coff + 24576;
    soff = (soff == 49152) ? 0 : soff + 24576;
  }
  TILE(NT - 1, coff, 0, false, "s_waitcnt vmcnt(0)")

#undef TILE
#undef MFMA4

  // epilogue.  D frag layout: col=l&15, row=(l>>4)*4+r  (verified R2)
  if constexpr (!FUSE) {
    float bb[4];
#pragma unroll
    for (int ni = 0; ni < 4; ++ni) bb[ni] = bias[tn + wc * 64 + ni * 16 + l15];
#pragma unroll
    for (int mi = 0; mi < 4; ++mi) {
#pragma unroll
      for (int r = 0; r < 4; ++r) {
        const int row = tm + wr * 64 + mi * 16 + lh * 4 + r;
#pragma unroll
        for (int ni = 0; ni < 4; ++ni) {       // 4 adjacent 32B stores / row
          const int col = tn + wc * 64 + ni * 16 + l15;
          float v = acc[mi][ni][r] + bb[ni];
          v = v / (1.f + __expf(-v));
          Cout[(size_t)row * 1024 + col] = f2bf(v);
        }
      }
    }
  } else {
    float bb[4], w3[4];
#pragma unroll
    for (int ni = 0; ni < 4; ++ni) {
      const int col = tn + wc * 64 + ni * 16 + l15;
      bb[ni] = bias[col];
      w3[ni] = W3[col];
    }
    float* vpart = (float*)lds;
    __syncthreads();
    if (tid < 128) vpart[tid] = 0.f;
    __syncthreads();
#pragma unroll
    for (int mi = 0; mi < 4; ++mi) {
#pragma unroll
      for (int r = 0; r < 4; ++r) {
        float s = 0.f;
#pragma unroll
        for (int ni = 0; ni < 4; ++ni) {
          float v = acc[mi][ni][r] + bb[ni];
          v = v / (1.f + __expf(-v));
          s += v * w3[ni];
        }
        s += __shfl_xor(s, 1);
        s += __shfl_xor(s, 2);
        s += __shfl_xor(s, 4);
        s += __shfl_xor(s, 8);                 // sum over 16-lane l15 group
        if (l15 == 0)
          atomicAdd(&vpart[wr * 64 + mi * 16 + lh * 4 + r], s);  // LDS atomic
      }
    }
    __syncthreads();
    if (tid < 128)
      value_part[(size_t)blockIdx.y * 16384 + tm + tid] = vpart[tid];
  }
}

// ---------------------------------------------------------------------------
// 3) Fused TD(lambda) scan + actor loss.  One block per batch row b.
//    Writes per-block partials (no atomics): accs_arr[b*2]={critic,actor}
// ---------------------------------------------------------------------------
__global__ __launch_bounds__(256) void td_actor(
    const float* __restrict__ value_part, const float* __restrict__ reward,
    const float* __restrict__ cont, const float* __restrict__ b3,
    const float* __restrict__ action, const float* __restrict__ a_mu,
    const float* __restrict__ a_sigma, float* __restrict__ accs_arr) {
  __shared__ float vv[64], rr[64], cc[64], adv_s[64];
  const int b = blockIdx.x, tid = threadIdx.x;
  if (tid < 64) {
    const int i = b * 64 + tid;
    vv[tid] = value_part[i] + value_part[16384 + i] + value_part[32768 + i] +
              value_part[49152 + i] + b3[0];
    rr[tid] = reward[i];
    cc[tid] = cont[i];
  }
  __syncthreads();
  if (tid == 0) {
    const float g = 0.99f, lam = 0.95f;
    float Rn = vv[63];
    adv_s[63] = 0.f;
    float s2 = 0.f;
    for (int t = 62; t >= 0; --t) {
      float R = rr[t] + g * cc[t] * ((1.f - lam) * vv[t + 1] + lam * Rn);
      float a = R - vv[t];
      adv_s[t] = a;
      s2 += a * a;
      Rn = R;
    }
    accs_arr[b * 2] = s2;
  }
  __syncthreads();
  const float C1 = 0.91893853320467274f;  // 0.5*log(2*pi)
  const float NU = 0.001f;
  const float av = adv_s[tid >> 2];
  const size_t base = (size_t)b * 4096 + tid * 16;
  float s = 0.f;
#pragma unroll
  for (int j = 0; j < 4; ++j) {
    f4v a  = *(const f4v*)(action  + base + j * 4);
    f4v mu = *(const f4v*)(a_mu    + base + j * 4);
    f4v sg = *(const f4v*)(a_sigma + base + j * 4);
#pragma unroll
    for (int i = 0; i < 4; ++i) {
      float d = (a[i] - mu[i]) / sg[i];
      float ls = __logf(sg[i]);
      float lp = -0.5f * d * d - ls - C1;
      s += lp * av + NU * (0.5f + C1 + ls);
    }
  }
#pragma unroll
  for (int off = 32; off; off >>= 1) s += __shfl_down(s, off);
  __shared__ float red[4];
  if ((tid & 63) == 0) red[tid >> 6] = s;
  __syncthreads();
  if (tid == 0) accs_arr[b * 2 + 1] = red[0] + red[1] + red[2] + red[3];
}

// ---------------------------------------------------------------------------
// 4) finalize: reduce 256 block-partials -> 2 losses
// ---------------------------------------------------------------------------
__global__ __launch_bounds__(256) void fin_kernel(
    const float* __restrict__ accs_arr, float* __restrict__ out) {
  const int tid = threadIdx.x;
  float c = accs_arr[tid * 2];
  float a = accs_arr[tid * 2 + 1];
#pragma unroll
  for (int off = 32; off; off >>= 1) {
    c += __shfl_down(c, off);
    a += __shfl_down(a, off);
  }
  __shared__ float rc[4], ra[4];
  if ((tid & 63) == 0) { rc[tid >> 6] = c; ra[tid >> 6] = a; }
  __syncthreads();
  if (tid == 0) {
    out[0] = -(ra[0] + ra[1] + ra[2] + ra[3]) / 1048576.0f;  // B*T*A
    out[1] = 0.5f * (rc[0] + rc[1] + rc[2] + rc[3]) / 16384.0f;
  }
}

// ---------------------------------------------------------------------------
extern "C" void kernel_launch(void* const* d_in, const int* in_sizes, int n_in,
                              void* d_out, int out_size, void* d_ws, size_t ws_size,
                              hipStream_t stream) {
  const float* h       = (const float*)d_in[0];
  const float* z       = (const float*)d_in[1];
  const float* reward  = (const float*)d_in[2];
  const float* cont    = (const float*)d_in[3];
  const float* action  = (const float*)d_in[4];
  const float* a_mu    = (const float*)d_in[5];
  const float* a_sigma = (const float*)d_in[6];
  const float* W1      = (const float*)d_in[7];
  const float* b1      = (const float*)d_in[8];
  const float* W2      = (const float*)d_in[9];
  const float* b2      = (const float*)d_in[10];
  const float* W3      = (const float*)d_in[11];
  const float* b3      = (const float*)d_in[12];

  char* ws = (char*)d_ws;
  unsigned short* X    = (unsigned short*)(ws);              // 48 MB
  unsigned short* W1T  = (unsigned short*)(ws + 50331648);   // 3 MB
  unsigned short* W2T  = (unsigned short*)(ws + 53477376);   // 2 MB
  unsigned short* X1   = (unsigned short*)(ws + 55574528);   // 32 MB
  float* value_part    = (float*)(ws + 89128960);            // 4x16384 f32
  float* accs_arr      = (float*)(ws + 89391104);            // 256x2 f32

  prep_all<<<14848, 256, 0, stream>>>(h, z, X, W1, W1T, W2, W2T);
  gemm128<1536, false><<<dim3(128, 4), 512, 0, stream>>>(X, W1T, b1, X1, nullptr, nullptr);
  gemm128<1024, true><<<dim3(128, 4), 512, 0, stream>>>(X1, W2T, b2, nullptr, W3, value_part);
  td_actor<<<256, 256, 0, stream>>>(value_part, reward, cont, b3, action, a_mu, a_sigma, accs_arr);
  fin_kernel<<<1, 256, 0, stream>>>(accs_arr, (float*)d_out);
}